// Round 15
// baseline (205.233 us; speedup 1.0000x reference)
//
#include <hip/hip_runtime.h>

#define D 128
#define FB2 1024      // edges per fill block (782 blocks: TLP for scatter phase)
#define CSTR 16       // cursor stride (ints) = one 64B line per bucket
#define CAPB 2816     // rec capacity per 128-dst bucket (mean 2048, +16 sigma)
#define SCAP 3456     // padded src-list capacity per 128-dst bucket
#define STAIL 3448    // run cap; slots 3448..3455 stay zoff pads
#define NREP 4        // stat-buffer replicas

typedef __attribute__((ext_vector_type(8))) short short8;
typedef __attribute__((ext_vector_type(4))) float f32x4;

union SP { int slist[SCAP]; float part[2048]; };

static __device__ __forceinline__ unsigned short f2bf(float f) {
    union { float f; unsigned u; } v; v.f = f;
    unsigned r = v.u + 0x7FFF + ((v.u >> 16) & 1);   // RNE
    return (unsigned short)(r >> 16);
}

static __device__ __forceinline__ float2 bfpair2f(unsigned p) {
    union { unsigned u; float f; } a, b;
    a.u = (p & 0xFFFFu) << 16;
    b.u = p & 0xFFFF0000u;
    return make_float2(a.f, b.f);
}

static __device__ __forceinline__ void acc2(f32x4& A, uint2 p) {
    union { unsigned u; float f; } t;
    float f0, f1, f2, f3;
    t.u = p.x << 16;          f0 = t.f;
    t.u = p.x & 0xFFFF0000u;  f1 = t.f;
    t.u = p.y << 16;          f2 = t.f;
    t.u = p.y & 0xFFFF0000u;  f3 = t.f;
    A[0] += f0; A[1] += f1; A[2] += f2; A[3] += f3;
}

// emit one gathered row into the fragment-ordered LDS A tile.
// XOR-swizzle row with k5=(kk<<2)|q (r9-verified): write spreads over 16 16B
// slots per 128B window (2-way conflict = free) instead of 2 (16-way).
static __device__ __forceinline__ void emitA(
    unsigned short* Al, int rloc, int valid,
    int e_kk, int e_q, int e_j0, float epsv, uint2 xv, f32x4 A)
{
    float r0 = 0.f, r1 = 0.f, r2 = 0.f, r3 = 0.f;
    if (valid) {
        union { unsigned u; float f; } t;
        float x0, x1, x2, x3;
        t.u = xv.x << 16;          x0 = t.f;
        t.u = xv.x & 0xFFFF0000u;  x1 = t.f;
        t.u = xv.y << 16;          x2 = t.f;
        t.u = xv.y & 0xFFFF0000u;  x3 = t.f;
        r0 = fmaf(epsv, x0, A[0]);
        r1 = fmaf(epsv, x1, A[1]);
        r2 = fmaf(epsv, x2, A[2]);
        r3 = fmaf(epsv, x3, A[3]);
    }
    uint2 o;
    o.x = (unsigned)f2bf(r0) | ((unsigned)f2bf(r1) << 16);
    o.y = (unsigned)f2bf(r2) | ((unsigned)f2bf(r3) << 16);
    int w = rloc >> 4, rl = rloc & 15;
    int k5 = (e_kk << 2) | e_q;
    unsigned addr = (unsigned)(w * 2048 + e_kk * 512 + e_q * 128
                               + ((rl ^ k5) << 3) + e_j0);
    *(uint2*)(Al + addr) = o;
}

// ------- fused prep + fill (fill blocks FIRST): edge fill into fixed-capacity
//         128-dst rec segments, then x->bf16, W->fragments, stats/zrow zero.
//         cursor: one 64B line per bucket (CSTR) -> parallel L2 atomic lines. -------
__global__ __launch_bounds__(256) void prep_fill_kernel(
    const float4* __restrict__ x4, uint2* __restrict__ xh, int xtotal,
    const float* __restrict__ W1, const float* __restrict__ W2,
    unsigned short* __restrict__ Wf1, unsigned short* __restrict__ Wf2,
    float* __restrict__ stats, unsigned short* __restrict__ zrow,
    int xblocks, int fblocks,
    const int* __restrict__ ei, int E, int NB,
    int* __restrict__ cursor, unsigned* __restrict__ rec)
{
    __shared__ int hist[512], base[512];
    int tid = threadIdx.x;

    if (blockIdx.x < (unsigned)fblocks) {
        // ---- fill range (scheduled first: the long pole) ----
        int b0 = (int)blockIdx.x * FB2;
        for (int i = tid; i < NB; i += 256) hist[i] = 0;
        __syncthreads();
        int lim = min(FB2, E - b0);
        for (int i = tid; i < lim; i += 256)
            atomicAdd(&hist[ei[E + b0 + i] >> 7], 1);
        __syncthreads();
        for (int i = tid; i < NB; i += 256) {
            int c = hist[i];
            base[i] = c ? atomicAdd(&cursor[i * CSTR], c) : 0;
            hist[i] = 0;   // reuse as rank counter
        }
        __syncthreads();
        for (int i = tid; i < lim; i += 256) {
            int e = b0 + i;
            int dst = ei[E + e], src = ei[e];
            int bk = dst >> 7;
            int r = atomicAdd(&hist[bk], 1);
            int slot = base[bk] + r;
            if (slot < CAPB)
                rec[(unsigned)bk * CAPB + slot] = ((unsigned)src << 7) | (unsigned)(dst & 127);
        }
        return;
    }
    int bx = (int)blockIdx.x - fblocks;
    if (bx < xblocks) {
        int i = bx * 256 + tid;
        if (i >= xtotal) return;
        float4 v = x4[i];
        uint2 o;
        o.x = (unsigned)f2bf(v.x) | ((unsigned)f2bf(v.y) << 16);
        o.y = (unsigned)f2bf(v.z) | ((unsigned)f2bf(v.w) << 16);
        xh[i] = o;
        return;
    }
    if (bx < xblocks + 128) {
        int idx = (bx - xblocks) * 256 + tid;   // 0..32767
        const float* W = (idx < 16384) ? W1 : W2;
        unsigned short* Wf = (idx < 16384) ? Wf1 : Wf2;
        int e = idx & 16383;
        int j = e & 7, lane = (e >> 3) & 63, ckk = e >> 9;
        int ct = ckk & 7, kk = ckk >> 3;
        int k = kk * 32 + (lane >> 4) * 8 + j;
        int n = ct * 16 + (lane & 15);
        Wf[e] = f2bf(W[k * 128 + n]);
        return;
    }
    // stats + zrow zero
    #pragma unroll
    for (int i = 0; i < 2 * NREP; ++i) stats[tid + i * 256] = 0.f;
    if (tid < 128) zrow[tid] = 0;
}

// ------- fused subsort + gather + GEMM1 + BN1-stat: one block per 128-dst bucket.
//         r8 gather structure + swizzled A tile + W-from-global (L2-broadcast).
//         LDS ~48.6 KB -> 3 blocks/CU. -------
__global__ __launch_bounds__(512) void fused_gather_gemm1_kernel(
    const unsigned* __restrict__ xh, const unsigned* __restrict__ rec,
    const int* __restrict__ cnt_g, const float* __restrict__ epsp,
    const unsigned short* __restrict__ Wf, const float* __restrict__ bias,
    unsigned short* __restrict__ z1out,
    float* __restrict__ stat_sum, float* __restrict__ stat_sq,
    int N, int zoff)
{
    __shared__ unsigned short Al[16384];   // 32 KB A fragments (8 tiles x 16 rows)
    __shared__ SP u;                       // slist (phase 1/2) | part (phase 3)
    __shared__ int cnt[128], rnk[128], offs[129];

    int tid = threadIdx.x;
    int g = blockIdx.x;
    int d0 = g << 7;

    if (tid < 128) { cnt[tid] = 0; rnk[tid] = 0; }
    for (int i = tid; i < SCAP; i += 512) u.slist[i] = zoff;
    __syncthreads();

    int cv = cnt_g[g * CSTR];
    if (cv > CAPB) cv = CAPB;
    int lo = g * CAPB, hi = lo + cv;

    for (int i = lo + tid; i < hi; i += 512)
        atomicAdd(&cnt[rec[i] & 127], 1);
    __syncthreads();
    if (tid == 0) {
        int run = 0;
        #pragma unroll
        for (int j = 0; j < 128; ++j) {
            offs[j] = run;
            run += (cnt[j] + 7) & ~7;          // pad runs to mult of 8
            if (run > STAIL) run = STAIL;
        }
        offs[128] = run;
    }
    __syncthreads();
    for (int i = lo + tid; i < hi; i += 512) {
        unsigned r = rec[i];
        int d = r & 127;
        int rk = atomicAdd(&rnk[d], 1);
        int slot = offs[d] + rk;
        if (slot < offs[d + 1]) u.slist[slot] = (int)((r >> 7) << 8);  // src*256
    }
    __syncthreads();

    int wv = tid >> 6, lane = tid & 63;
    int half = lane >> 5, l5 = lane & 31;
    unsigned lane8 = (unsigned)(l5 << 3);
    float epsv = 1.0f + __ldg(epsp);
    const char* xc = (const char*)xh;

    // emit-address components for lane l5 (owns cols c0 = l5*4 .. c0+3)
    int e_kk = l5 >> 3;
    int e_q  = (l5 >> 1) & 3;
    int e_j0 = (l5 & 1) * 4;

    #pragma unroll 1
    for (int p = 0; p < 4; ++p) {
        int dloc = p * 32 + wv * 4;
        int dA = d0 + dloc, dB = dA + 1, dC = dA + 2, dD = dA + 3;
        int vA = (dA < N), vB = (dB < N), vC = (dC < N), vD = (dD < N);

        int s0 = offs[dloc + 0], s1 = offs[dloc + 1];
        int s2 = offs[dloc + 2], s3 = offs[dloc + 3], s4 = offs[dloc + 4];
        int nch0 = (s1 - s0) >> 3, nch1 = (s2 - s1) >> 3;
        int nch2 = (s3 - s2) >> 3, nch3 = (s4 - s3) >> 3;
        int iters = max(max(nch0, nch1), max(nch2, nch3));

        uint2 xv0 = *(const uint2*)(xc + (unsigned)((vA ? dA : 0) * 256) + lane8);
        uint2 xv1 = *(const uint2*)(xc + (unsigned)((vB ? dB : 0) * 256) + lane8);
        uint2 xv2 = *(const uint2*)(xc + (unsigned)((vC ? dC : 0) * 256) + lane8);
        uint2 xv3 = *(const uint2*)(xc + (unsigned)((vD ? dD : 0) * 256) + lane8);

        f32x4 A0 = (f32x4){0.f, 0.f, 0.f, 0.f};
        f32x4 A1 = (f32x4){0.f, 0.f, 0.f, 0.f};
        f32x4 A2 = (f32x4){0.f, 0.f, 0.f, 0.f};
        f32x4 A3 = (f32x4){0.f, 0.f, 0.f, 0.f};

        for (int c = 0; c < iters; ++c) {
            int b0 = (c < nch0) ? (s0 + (c << 3)) : STAIL;   // STAIL.. = zoff pads
            int b1 = (c < nch1) ? (s1 + (c << 3)) : STAIL;
            int b2 = (c < nch2) ? (s2 + (c << 3)) : STAIL;
            int b3 = (c < nch3) ? (s3 + (c << 3)) : STAIL;
            uint2 p0[4], p1[4], p2[4], p3[4];
            #pragma unroll
            for (int k = 0; k < 4; ++k) {
                unsigned o0 = (unsigned)u.slist[b0 + 2 * k + half];
                unsigned o1 = (unsigned)u.slist[b1 + 2 * k + half];
                unsigned o2 = (unsigned)u.slist[b2 + 2 * k + half];
                unsigned o3 = (unsigned)u.slist[b3 + 2 * k + half];
                p0[k] = *(const uint2*)(xc + (o0 + lane8));
                p1[k] = *(const uint2*)(xc + (o1 + lane8));
                p2[k] = *(const uint2*)(xc + (o2 + lane8));
                p3[k] = *(const uint2*)(xc + (o3 + lane8));
            }
            #pragma unroll
            for (int k = 0; k < 4; ++k) {
                acc2(A0, p0[k]); acc2(A1, p1[k]);
                acc2(A2, p2[k]); acc2(A3, p3[k]);
            }
        }

        #pragma unroll
        for (int r = 0; r < 4; ++r) {
            A0[r] += __shfl_xor(A0[r], 32, 64);
            A1[r] += __shfl_xor(A1[r], 32, 64);
            A2[r] += __shfl_xor(A2[r], 32, 64);
            A3[r] += __shfl_xor(A3[r], 32, 64);
        }

        if (half == 0) {
            emitA(Al, dloc + 0, vA, e_kk, e_q, e_j0, epsv, xv0, A0);
            emitA(Al, dloc + 1, vB, e_kk, e_q, e_j0, epsv, xv1, A1);
            emitA(Al, dloc + 2, vC, e_kk, e_q, e_j0, epsv, xv2, A2);
            emitA(Al, dloc + 3, vD, e_kk, e_q, e_j0, epsv, xv3, A3);
        }
    }
    __syncthreads();   // A tile complete; slist dead (part may alias now)

    // ---- MFMA phase: wave wv owns rows d0+wv*16..+15; B from global Wf ----
    int q = lane >> 4, n16 = lane & 15;
    f32x4 acc[8];
    #pragma unroll
    for (int ct = 0; ct < 8; ++ct) acc[ct] = (f32x4){0.f, 0.f, 0.f, 0.f};

    #pragma unroll
    for (int kk = 0; kk < 4; ++kk) {
        int k5 = (kk << 2) | q;
        short8 af = *(const short8*)&Al[wv * 2048 + kk * 512 + q * 128
                                        + ((n16 ^ k5) << 3)];
        #pragma unroll
        for (int ct = 0; ct < 8; ++ct) {
            short8 bf = *(const short8*)&Wf[(((kk * 8 + ct) * 64) + lane) * 8];
            acc[ct] = __builtin_amdgcn_mfma_f32_16x16x32_bf16(af, bf, acc[ct], 0, 0, 0);
        }
    }

    int rowb = d0 + wv * 16;
    #pragma unroll
    for (int ct = 0; ct < 8; ++ct) {
        int col = ct * 16 + n16;
        float bv = __ldg(bias + col);
        float s = 0.f, qs = 0.f;
        #pragma unroll
        for (int reg = 0; reg < 4; ++reg) {
            int row = rowb + q * 4 + reg;
            float v = acc[ct][reg] + bv;
            if (row < N) {
                z1out[(size_t)row * D + col] = f2bf(v);
                s += v;
                qs = fmaf(v, v, qs);
            }
        }
        s  += __shfl_xor(s, 16, 64);
        s  += __shfl_xor(s, 32, 64);
        qs += __shfl_xor(qs, 16, 64);
        qs += __shfl_xor(qs, 32, 64);
        if (lane < 16) {
            u.part[wv * 128 + col] = s;
            u.part[1024 + wv * 128 + col] = qs;
        }
    }
    __syncthreads();

    if (tid < 128) {
        float s = 0.f, qq = 0.f;
        #pragma unroll
        for (int w = 0; w < 8; ++w) {
            s  += u.part[w * 128 + tid];
            qq += u.part[1024 + w * 128 + tid];
        }
        int rep = ((int)blockIdx.x & (NREP - 1)) * 512;
        atomicAdd(&stat_sum[rep + tid], s);
        atomicAdd(&stat_sq[rep + tid], qq);
    }
}

static __device__ __forceinline__ short8 bn_relu_pack(
    const unsigned short* arow, int c, const float* scf, const float* shf)
{
    uint4 rw = *(const uint4*)(arow + c);
    float2 p0 = bfpair2f(rw.x), p1 = bfpair2f(rw.y);
    float2 p2 = bfpair2f(rw.z), p3 = bfpair2f(rw.w);
    p0.x = fmaxf(fmaf(p0.x, scf[c + 0], shf[c + 0]), 0.f);
    p0.y = fmaxf(fmaf(p0.y, scf[c + 1], shf[c + 1]), 0.f);
    p1.x = fmaxf(fmaf(p1.x, scf[c + 2], shf[c + 2]), 0.f);
    p1.y = fmaxf(fmaf(p1.y, scf[c + 3], shf[c + 3]), 0.f);
    p2.x = fmaxf(fmaf(p2.x, scf[c + 4], shf[c + 4]), 0.f);
    p2.y = fmaxf(fmaf(p2.y, scf[c + 5], shf[c + 5]), 0.f);
    p3.x = fmaxf(fmaf(p3.x, scf[c + 6], shf[c + 6]), 0.f);
    p3.y = fmaxf(fmaf(p3.y, scf[c + 7], shf[c + 7]), 0.f);
    short8 af;
    af[0] = (short)f2bf(p0.x); af[1] = (short)f2bf(p0.y);
    af[2] = (short)f2bf(p1.x); af[3] = (short)f2bf(p1.y);
    af[4] = (short)f2bf(p2.x); af[5] = (short)f2bf(p2.y);
    af[6] = (short)f2bf(p3.x); af[7] = (short)f2bf(p3.y);
    return af;
}

// ---- MFMA GEMM2 + BN2-stat (bf16 in/out), fused BN1 finalize; W from global ----
__global__ __launch_bounds__(256) void gemm_bn_mfma_kernel(
    const unsigned short* __restrict__ a_bf,
    const float* __restrict__ stat_in, const float* __restrict__ gamma,
    const float* __restrict__ beta, float invN,
    const unsigned short* __restrict__ Wf, const float* __restrict__ bias,
    unsigned short* __restrict__ zout,
    float* __restrict__ stat_sum, float* __restrict__ stat_sq,
    int N, int mode)
{
    __shared__ float part[1024];
    __shared__ float scf[128], shf[128];

    int tid = threadIdx.x;
    if (mode == 1 && tid < 128) {          // fused BN finalize (sum replicas)
        float ssum = 0.f, sqs = 0.f;
        #pragma unroll
        for (int r = 0; r < NREP; ++r) {
            ssum += stat_in[r * 512 + tid];
            sqs  += stat_in[r * 512 + 128 + tid];
        }
        float mean = ssum * invN;
        float var  = sqs * invN - mean * mean;
        float sv = gamma[tid] * rsqrtf(var + 1e-5f);
        scf[tid] = sv;
        shf[tid] = fmaf(-mean, sv, beta[tid]);
    }
    __syncthreads();

    int w = tid >> 6, lane = tid & 63, q = lane >> 4, n16 = lane & 15;
    int rowb = blockIdx.x * 128 + w * 16;
    int m0 = rowb + n16;
    int m1 = rowb + 64 + n16;
    int mc0 = (m0 < N) ? m0 : (N - 1);
    int mc1 = (m1 < N) ? m1 : (N - 1);
    const unsigned short* arow0 = a_bf + (size_t)mc0 * D;
    const unsigned short* arow1 = a_bf + (size_t)mc1 * D;

    f32x4 acc0[8], acc1[8];
    #pragma unroll
    for (int ct = 0; ct < 8; ++ct) {
        acc0[ct] = (f32x4){0.f, 0.f, 0.f, 0.f};
        acc1[ct] = (f32x4){0.f, 0.f, 0.f, 0.f};
    }

    #pragma unroll
    for (int kk = 0; kk < 4; ++kk) {
        int c = kk * 32 + q * 8;
        short8 af0, af1;
        if (mode == 0) {
            af0 = *(const short8*)(arow0 + c);
            af1 = *(const short8*)(arow1 + c);
        } else {
            af0 = bn_relu_pack(arow0, c, scf, shf);
            af1 = bn_relu_pack(arow1, c, scf, shf);
        }
        #pragma unroll
        for (int ct = 0; ct < 8; ++ct) {
            short8 bf = *(const short8*)&Wf[(((kk * 8 + ct) * 64) + lane) * 8];
            acc0[ct] = __builtin_amdgcn_mfma_f32_16x16x32_bf16(af0, bf, acc0[ct], 0, 0, 0);
            acc1[ct] = __builtin_amdgcn_mfma_f32_16x16x32_bf16(af1, bf, acc1[ct], 0, 0, 0);
        }
    }

    // epilogue: bias add, bf16 store, per-column stats (from fp32 values)
    #pragma unroll
    for (int ct = 0; ct < 8; ++ct) {
        int col = ct * 16 + n16;
        float bv = __ldg(bias + col);
        float s = 0.f, qs = 0.f;
        #pragma unroll
        for (int reg = 0; reg < 4; ++reg) {
            int row = rowb + q * 4 + reg;
            float v = acc0[ct][reg] + bv;
            if (row < N) {
                zout[(size_t)row * D + col] = f2bf(v);
                s += v;
                qs = fmaf(v, v, qs);
            }
        }
        #pragma unroll
        for (int reg = 0; reg < 4; ++reg) {
            int row = rowb + 64 + q * 4 + reg;
            float v = acc1[ct][reg] + bv;
            if (row < N) {
                zout[(size_t)row * D + col] = f2bf(v);
                s += v;
                qs = fmaf(v, v, qs);
            }
        }
        s  += __shfl_xor(s, 16, 64);
        s  += __shfl_xor(s, 32, 64);
        qs += __shfl_xor(qs, 16, 64);
        qs += __shfl_xor(qs, 32, 64);
        if (lane < 16) {
            part[w * 128 + col] = s;
            part[512 + w * 128 + col] = qs;
        }
    }
    __syncthreads();

    if (tid < 128) {
        int rep = ((int)blockIdx.x & (NREP - 1)) * 512;
        float s  = part[tid] + part[128 + tid] + part[256 + tid] + part[384 + tid];
        float qq = part[512 + tid] + part[640 + tid] + part[768 + tid] + part[896 + tid];
        atomicAdd(&stat_sum[rep + tid], s);
        atomicAdd(&stat_sq[rep + tid], qq);
    }
}

// ------- final BN + ReLU (fused BN2 finalize, sums NREP replicas) -------
__global__ __launch_bounds__(256) void bn_relu_kernel(
    const uint2* __restrict__ z2, float4* __restrict__ out,
    const float* __restrict__ stat2, const float* __restrict__ gamma,
    const float* __restrict__ beta, float invN, int total4)
{
    __shared__ float sf[128], tf[128];
    int tid = threadIdx.x;
    if (tid < 128) {
        float ssum = 0.f, sqs = 0.f;
        #pragma unroll
        for (int r = 0; r < NREP; ++r) {
            ssum += stat2[r * 512 + tid];
            sqs  += stat2[r * 512 + 128 + tid];
        }
        float mean = ssum * invN;
        float var  = sqs * invN - mean * mean;
        float sv = gamma[tid] * rsqrtf(var + 1e-5f);
        sf[tid] = sv;
        tf[tid] = fmaf(-mean, sv, beta[tid]);
    }
    __syncthreads();

    int i = blockIdx.x * 256 + tid;
    if (i >= total4) return;
    uint2 zp = z2[i];
    float2 v01 = bfpair2f(zp.x);
    float2 v23 = bfpair2f(zp.y);
    int c = (i & 31) * 4;
    float4 o;
    o.x = fmaxf(fmaf(v01.x, sf[c + 0], tf[c + 0]), 0.f);
    o.y = fmaxf(fmaf(v01.y, sf[c + 1], tf[c + 1]), 0.f);
    o.z = fmaxf(fmaf(v23.x, sf[c + 2], tf[c + 2]), 0.f);
    o.w = fmaxf(fmaf(v23.y, sf[c + 3], tf[c + 3]), 0.f);
    out[i] = o;
}

extern "C" void kernel_launch(void* const* d_in, const int* in_sizes, int n_in,
                              void* d_out, int out_size, void* d_ws, size_t ws_size,
                              hipStream_t stream)
{
    const float* x   = (const float*)d_in[0];
    const int*   ei  = (const int*)d_in[1];
    const float* eps = (const float*)d_in[2];
    const float* W1  = (const float*)d_in[3];
    const float* b1  = (const float*)d_in[4];
    const float* g1  = (const float*)d_in[5];
    const float* be1 = (const float*)d_in[6];
    const float* W2  = (const float*)d_in[7];
    const float* b2  = (const float*)d_in[8];
    const float* g2  = (const float*)d_in[9];
    const float* be2 = (const float*)d_in[10];

    int N = in_sizes[0] / D;       // 50000
    int E = in_sizes[1] / 2;       // 800000
    size_t ND = (size_t)N * D;
    int NB  = (N + 127) >> 7;      // 391 128-dst buckets

    // workspace layout (~25.8 MB):
    //   xh: ND+128 ushorts (row N = zeros); live through fused kernel
    //   region2 (ND ushorts): rec = NB*CAPB ints (4.4 MB) @ +0;
    //                         cursor (NB*CSTR ints, line-padded) @ +8 MB
    //                         -> z2 reuses region2 (gemm2+; rec/cursor dead)
    //   stats: NREP*512 floats, then Wf1/Wf2
    //   z1 lives in d_out (bf16, dead once bn_relu writes final fp32)
    unsigned short* xh  = (unsigned short*)d_ws;
    unsigned short* region2 = xh + ND + 128;
    unsigned* rec       = (unsigned*)region2;
    unsigned short* z2  = region2;
    int* cursor         = (int*)((char*)region2 + (8 << 20));
    float* stats        = (float*)(region2 + ND);
    unsigned short* Wf1 = (unsigned short*)(stats + 2 * NREP * 256);
    unsigned short* Wf2 = Wf1 + 16384;

    float* sum1 = stats + 0,   *sq1 = stats + 128;     // replica 0 bases
    float* sum2 = stats + 256, *sq2 = stats + 384;
    unsigned short* z1 = (unsigned short*)d_out;

    hipMemsetAsync(cursor, 0, NB * CSTR * sizeof(int), stream);

    int xtotal = N * 32;                      // float4 groups in x
    int xblocks = (xtotal + 255) / 256;
    int fblocks = (E + FB2 - 1) / FB2;        // 782 fill blocks
    prep_fill_kernel<<<fblocks + xblocks + 129, 256, 0, stream>>>(
        (const float4*)x, (uint2*)xh, xtotal, W1, W2, Wf1, Wf2,
        stats, xh + ND, xblocks, fblocks, ei, E, NB, cursor, rec);

    fused_gather_gemm1_kernel<<<NB, 512, 0, stream>>>(
        (const unsigned*)xh, rec, cursor, eps, Wf1, b1,
        z1, sum1, sq1, N, N * 256);

    int gblocks = (N + 127) / 128;
    gemm_bn_mfma_kernel<<<gblocks, 256, 0, stream>>>(
        z1, sum1, g1, be1, 1.0f / N,
        Wf2, b2, z2, sum2, sq2, N, 1);
    bn_relu_kernel<<<(N * 32 + 255) / 256, 256, 0, stream>>>(
        (const uint2*)z2, (float4*)d_out, sum2, g2, be2, 1.0f / N, N * 32);
}

// Round 16
// 198.026 us; speedup vs baseline: 1.0364x; 1.0364x over previous
//
#include <hip/hip_runtime.h>

#define D 128
#define FB2 1024      // edges per fill block (782 blocks: TLP for scatter phase)
#define CSTR 16       // cursor stride (ints) = one 64B line per bucket
#define CAPB 2816     // rec capacity per 128-dst bucket (mean 2048, +16 sigma)
#define SCAP 3456     // padded src-list capacity per 128-dst bucket
#define STAIL 3448    // run cap; slots 3448..3455 stay zoff pads
#define NREP 4        // stat-buffer replicas

typedef __attribute__((ext_vector_type(8))) short short8;
typedef __attribute__((ext_vector_type(4))) float f32x4;

union SP { int slist[SCAP]; float part[2048]; };

static __device__ __forceinline__ unsigned short f2bf(float f) {
    union { float f; unsigned u; } v; v.f = f;
    unsigned r = v.u + 0x7FFF + ((v.u >> 16) & 1);   // RNE
    return (unsigned short)(r >> 16);
}

static __device__ __forceinline__ float2 bfpair2f(unsigned p) {
    union { unsigned u; float f; } a, b;
    a.u = (p & 0xFFFFu) << 16;
    b.u = p & 0xFFFF0000u;
    return make_float2(a.f, b.f);
}

static __device__ __forceinline__ void acc2(f32x4& A, uint2 p) {
    union { unsigned u; float f; } t;
    float f0, f1, f2, f3;
    t.u = p.x << 16;          f0 = t.f;
    t.u = p.x & 0xFFFF0000u;  f1 = t.f;
    t.u = p.y << 16;          f2 = t.f;
    t.u = p.y & 0xFFFF0000u;  f3 = t.f;
    A[0] += f0; A[1] += f1; A[2] += f2; A[3] += f3;
}

// emit one gathered row into the fragment-ordered LDS A tile.
// XOR-swizzle row with k5=(kk<<2)|q: write spreads over 16 16B slots per
// 128B window (2-way conflict = free) instead of 2 (16-way). Single change
// vs the 199.4us base; r15 verified mechanism (conflicts 990K->290K) + safety.
static __device__ __forceinline__ void emitA(
    unsigned short* Al, int rloc, int valid,
    int e_kk, int e_q, int e_j0, float epsv, uint2 xv, f32x4 A)
{
    float r0 = 0.f, r1 = 0.f, r2 = 0.f, r3 = 0.f;
    if (valid) {
        union { unsigned u; float f; } t;
        float x0, x1, x2, x3;
        t.u = xv.x << 16;          x0 = t.f;
        t.u = xv.x & 0xFFFF0000u;  x1 = t.f;
        t.u = xv.y << 16;          x2 = t.f;
        t.u = xv.y & 0xFFFF0000u;  x3 = t.f;
        r0 = fmaf(epsv, x0, A[0]);
        r1 = fmaf(epsv, x1, A[1]);
        r2 = fmaf(epsv, x2, A[2]);
        r3 = fmaf(epsv, x3, A[3]);
    }
    uint2 o;
    o.x = (unsigned)f2bf(r0) | ((unsigned)f2bf(r1) << 16);
    o.y = (unsigned)f2bf(r2) | ((unsigned)f2bf(r3) << 16);
    int w = rloc >> 4, rl = rloc & 15;
    int k5 = (e_kk << 2) | e_q;
    unsigned addr = (unsigned)(w * 2048 + e_kk * 512 + e_q * 128
                               + ((rl ^ k5) << 3) + e_j0);
    *(uint2*)(Al + addr) = o;
}

// ------- fused prep + fill (fill blocks FIRST): edge fill into fixed-capacity
//         128-dst rec segments, then x->bf16, W->fragments, stats/zrow zero.
//         cursor: one 64B line per bucket (CSTR) -> parallel L2 atomic lines. -------
__global__ __launch_bounds__(256) void prep_fill_kernel(
    const float4* __restrict__ x4, uint2* __restrict__ xh, int xtotal,
    const float* __restrict__ W1, const float* __restrict__ W2,
    unsigned short* __restrict__ Wf1, unsigned short* __restrict__ Wf2,
    float* __restrict__ stats, unsigned short* __restrict__ zrow,
    int xblocks, int fblocks,
    const int* __restrict__ ei, int E, int NB,
    int* __restrict__ cursor, unsigned* __restrict__ rec)
{
    __shared__ int hist[512], base[512];
    int tid = threadIdx.x;

    if (blockIdx.x < (unsigned)fblocks) {
        // ---- fill range (scheduled first: the long pole) ----
        int b0 = (int)blockIdx.x * FB2;
        for (int i = tid; i < NB; i += 256) hist[i] = 0;
        __syncthreads();
        int lim = min(FB2, E - b0);
        for (int i = tid; i < lim; i += 256)
            atomicAdd(&hist[ei[E + b0 + i] >> 7], 1);
        __syncthreads();
        for (int i = tid; i < NB; i += 256) {
            int c = hist[i];
            base[i] = c ? atomicAdd(&cursor[i * CSTR], c) : 0;
            hist[i] = 0;   // reuse as rank counter
        }
        __syncthreads();
        for (int i = tid; i < lim; i += 256) {
            int e = b0 + i;
            int dst = ei[E + e], src = ei[e];
            int bk = dst >> 7;
            int r = atomicAdd(&hist[bk], 1);
            int slot = base[bk] + r;
            if (slot < CAPB)
                rec[(unsigned)bk * CAPB + slot] = ((unsigned)src << 7) | (unsigned)(dst & 127);
        }
        return;
    }
    int bx = (int)blockIdx.x - fblocks;
    if (bx < xblocks) {
        int i = bx * 256 + tid;
        if (i >= xtotal) return;
        float4 v = x4[i];
        uint2 o;
        o.x = (unsigned)f2bf(v.x) | ((unsigned)f2bf(v.y) << 16);
        o.y = (unsigned)f2bf(v.z) | ((unsigned)f2bf(v.w) << 16);
        xh[i] = o;
        return;
    }
    if (bx < xblocks + 128) {
        int idx = (bx - xblocks) * 256 + tid;   // 0..32767
        const float* W = (idx < 16384) ? W1 : W2;
        unsigned short* Wf = (idx < 16384) ? Wf1 : Wf2;
        int e = idx & 16383;
        int j = e & 7, lane = (e >> 3) & 63, ckk = e >> 9;
        int ct = ckk & 7, kk = ckk >> 3;
        int k = kk * 32 + (lane >> 4) * 8 + j;
        int n = ct * 16 + (lane & 15);
        Wf[e] = f2bf(W[k * 128 + n]);
        return;
    }
    // stats + zrow zero
    #pragma unroll
    for (int i = 0; i < 2 * NREP; ++i) stats[tid + i * 256] = 0.f;
    if (tid < 128) zrow[tid] = 0;
}

// ------- fused subsort + gather + GEMM1 + BN1-stat: one block per 128-dst bucket.
//         r8 structure (W-in-LDS, best measured) + swizzled A tile ONLY. -------
__global__ __launch_bounds__(512) void fused_gather_gemm1_kernel(
    const unsigned* __restrict__ xh, const unsigned* __restrict__ rec,
    const int* __restrict__ cnt_g, const float* __restrict__ epsp,
    const unsigned short* __restrict__ Wf, const float* __restrict__ bias,
    unsigned short* __restrict__ z1out,
    float* __restrict__ stat_sum, float* __restrict__ stat_sq,
    int N, int zoff)
{
    __shared__ unsigned short Wl[16384];   // 32 KB W fragments
    __shared__ unsigned short Al[16384];   // 32 KB A fragments (8 tiles x 16 rows)
    __shared__ SP u;                       // slist (phase 1/2) | part (phase 3)
    __shared__ int cnt[128], rnk[128], offs[129];

    int tid = threadIdx.x;
    int g = blockIdx.x;
    int d0 = g << 7;

    {   // stage W: 2048 float4 over 512 threads
        float4* dst = (float4*)Wl;
        const float4* srcp = (const float4*)Wf;
        #pragma unroll
        for (int i = 0; i < 4; ++i) dst[tid + i * 512] = srcp[tid + i * 512];
    }
    if (tid < 128) { cnt[tid] = 0; rnk[tid] = 0; }
    for (int i = tid; i < SCAP; i += 512) u.slist[i] = zoff;
    __syncthreads();

    int cv = cnt_g[g * CSTR];
    if (cv > CAPB) cv = CAPB;
    int lo = g * CAPB, hi = lo + cv;

    for (int i = lo + tid; i < hi; i += 512)
        atomicAdd(&cnt[rec[i] & 127], 1);
    __syncthreads();
    if (tid == 0) {
        int run = 0;
        #pragma unroll
        for (int j = 0; j < 128; ++j) {
            offs[j] = run;
            run += (cnt[j] + 7) & ~7;          // pad runs to mult of 8
            if (run > STAIL) run = STAIL;
        }
        offs[128] = run;
    }
    __syncthreads();
    for (int i = lo + tid; i < hi; i += 512) {
        unsigned r = rec[i];
        int d = r & 127;
        int rk = atomicAdd(&rnk[d], 1);
        int slot = offs[d] + rk;
        if (slot < offs[d + 1]) u.slist[slot] = (int)((r >> 7) << 8);  // src*256
    }
    __syncthreads();

    int wv = tid >> 6, lane = tid & 63;
    int half = lane >> 5, l5 = lane & 31;
    unsigned lane8 = (unsigned)(l5 << 3);
    float epsv = 1.0f + __ldg(epsp);
    const char* xc = (const char*)xh;

    // emit-address components for lane l5 (owns cols c0 = l5*4 .. c0+3)
    int e_kk = l5 >> 3;
    int e_q  = (l5 >> 1) & 3;
    int e_j0 = (l5 & 1) * 4;

    #pragma unroll 1
    for (int p = 0; p < 4; ++p) {
        int dloc = p * 32 + wv * 4;
        int dA = d0 + dloc, dB = dA + 1, dC = dA + 2, dD = dA + 3;
        int vA = (dA < N), vB = (dB < N), vC = (dC < N), vD = (dD < N);

        int s0 = offs[dloc + 0], s1 = offs[dloc + 1];
        int s2 = offs[dloc + 2], s3 = offs[dloc + 3], s4 = offs[dloc + 4];
        int nch0 = (s1 - s0) >> 3, nch1 = (s2 - s1) >> 3;
        int nch2 = (s3 - s2) >> 3, nch3 = (s4 - s3) >> 3;
        int iters = max(max(nch0, nch1), max(nch2, nch3));

        uint2 xv0 = *(const uint2*)(xc + (unsigned)((vA ? dA : 0) * 256) + lane8);
        uint2 xv1 = *(const uint2*)(xc + (unsigned)((vB ? dB : 0) * 256) + lane8);
        uint2 xv2 = *(const uint2*)(xc + (unsigned)((vC ? dC : 0) * 256) + lane8);
        uint2 xv3 = *(const uint2*)(xc + (unsigned)((vD ? dD : 0) * 256) + lane8);

        f32x4 A0 = (f32x4){0.f, 0.f, 0.f, 0.f};
        f32x4 A1 = (f32x4){0.f, 0.f, 0.f, 0.f};
        f32x4 A2 = (f32x4){0.f, 0.f, 0.f, 0.f};
        f32x4 A3 = (f32x4){0.f, 0.f, 0.f, 0.f};

        for (int c = 0; c < iters; ++c) {
            int b0 = (c < nch0) ? (s0 + (c << 3)) : STAIL;   // STAIL.. = zoff pads
            int b1 = (c < nch1) ? (s1 + (c << 3)) : STAIL;
            int b2 = (c < nch2) ? (s2 + (c << 3)) : STAIL;
            int b3 = (c < nch3) ? (s3 + (c << 3)) : STAIL;
            uint2 p0[4], p1[4], p2[4], p3[4];
            #pragma unroll
            for (int k = 0; k < 4; ++k) {
                unsigned o0 = (unsigned)u.slist[b0 + 2 * k + half];
                unsigned o1 = (unsigned)u.slist[b1 + 2 * k + half];
                unsigned o2 = (unsigned)u.slist[b2 + 2 * k + half];
                unsigned o3 = (unsigned)u.slist[b3 + 2 * k + half];
                p0[k] = *(const uint2*)(xc + (o0 + lane8));
                p1[k] = *(const uint2*)(xc + (o1 + lane8));
                p2[k] = *(const uint2*)(xc + (o2 + lane8));
                p3[k] = *(const uint2*)(xc + (o3 + lane8));
            }
            #pragma unroll
            for (int k = 0; k < 4; ++k) {
                acc2(A0, p0[k]); acc2(A1, p1[k]);
                acc2(A2, p2[k]); acc2(A3, p3[k]);
            }
        }

        #pragma unroll
        for (int r = 0; r < 4; ++r) {
            A0[r] += __shfl_xor(A0[r], 32, 64);
            A1[r] += __shfl_xor(A1[r], 32, 64);
            A2[r] += __shfl_xor(A2[r], 32, 64);
            A3[r] += __shfl_xor(A3[r], 32, 64);
        }

        if (half == 0) {
            emitA(Al, dloc + 0, vA, e_kk, e_q, e_j0, epsv, xv0, A0);
            emitA(Al, dloc + 1, vB, e_kk, e_q, e_j0, epsv, xv1, A1);
            emitA(Al, dloc + 2, vC, e_kk, e_q, e_j0, epsv, xv2, A2);
            emitA(Al, dloc + 3, vD, e_kk, e_q, e_j0, epsv, xv3, A3);
        }
    }
    __syncthreads();   // A tile complete; slist dead (part may alias now)

    // ---- MFMA phase: wave wv owns rows d0+wv*16..+15; swizzled A read ----
    int q = lane >> 4, n16 = lane & 15;
    f32x4 acc[8];
    #pragma unroll
    for (int ct = 0; ct < 8; ++ct) acc[ct] = (f32x4){0.f, 0.f, 0.f, 0.f};

    #pragma unroll
    for (int kk = 0; kk < 4; ++kk) {
        int k5 = (kk << 2) | q;
        short8 af = *(const short8*)&Al[wv * 2048 + kk * 512 + q * 128
                                        + ((n16 ^ k5) << 3)];
        #pragma unroll
        for (int ct = 0; ct < 8; ++ct) {
            short8 bf = *(const short8*)&Wl[(((kk * 8 + ct) * 64) + lane) * 8];
            acc[ct] = __builtin_amdgcn_mfma_f32_16x16x32_bf16(af, bf, acc[ct], 0, 0, 0);
        }
    }

    int rowb = d0 + wv * 16;
    #pragma unroll
    for (int ct = 0; ct < 8; ++ct) {
        int col = ct * 16 + n16;
        float bv = __ldg(bias + col);
        float s = 0.f, qs = 0.f;
        #pragma unroll
        for (int reg = 0; reg < 4; ++reg) {
            int row = rowb + q * 4 + reg;
            float v = acc[ct][reg] + bv;
            if (row < N) {
                z1out[(size_t)row * D + col] = f2bf(v);
                s += v;
                qs = fmaf(v, v, qs);
            }
        }
        s  += __shfl_xor(s, 16, 64);
        s  += __shfl_xor(s, 32, 64);
        qs += __shfl_xor(qs, 16, 64);
        qs += __shfl_xor(qs, 32, 64);
        if (lane < 16) {
            u.part[wv * 128 + col] = s;
            u.part[1024 + wv * 128 + col] = qs;
        }
    }
    __syncthreads();

    if (tid < 128) {
        float s = 0.f, qq = 0.f;
        #pragma unroll
        for (int w = 0; w < 8; ++w) {
            s  += u.part[w * 128 + tid];
            qq += u.part[1024 + w * 128 + tid];
        }
        int rep = ((int)blockIdx.x & (NREP - 1)) * 512;
        atomicAdd(&stat_sum[rep + tid], s);
        atomicAdd(&stat_sq[rep + tid], qq);
    }
}

static __device__ __forceinline__ short8 bn_relu_pack(
    const unsigned short* arow, int c, const float* scf, const float* shf)
{
    uint4 rw = *(const uint4*)(arow + c);
    float2 p0 = bfpair2f(rw.x), p1 = bfpair2f(rw.y);
    float2 p2 = bfpair2f(rw.z), p3 = bfpair2f(rw.w);
    p0.x = fmaxf(fmaf(p0.x, scf[c + 0], shf[c + 0]), 0.f);
    p0.y = fmaxf(fmaf(p0.y, scf[c + 1], shf[c + 1]), 0.f);
    p1.x = fmaxf(fmaf(p1.x, scf[c + 2], shf[c + 2]), 0.f);
    p1.y = fmaxf(fmaf(p1.y, scf[c + 3], shf[c + 3]), 0.f);
    p2.x = fmaxf(fmaf(p2.x, scf[c + 4], shf[c + 4]), 0.f);
    p2.y = fmaxf(fmaf(p2.y, scf[c + 5], shf[c + 5]), 0.f);
    p3.x = fmaxf(fmaf(p3.x, scf[c + 6], shf[c + 6]), 0.f);
    p3.y = fmaxf(fmaf(p3.y, scf[c + 7], shf[c + 7]), 0.f);
    short8 af;
    af[0] = (short)f2bf(p0.x); af[1] = (short)f2bf(p0.y);
    af[2] = (short)f2bf(p1.x); af[3] = (short)f2bf(p1.y);
    af[4] = (short)f2bf(p2.x); af[5] = (short)f2bf(p2.y);
    af[6] = (short)f2bf(p3.x); af[7] = (short)f2bf(p3.y);
    return af;
}

// ---------------- MFMA GEMM2 + BN2-stat (bf16 in/out), fused BN1 finalize ----------------
__global__ __launch_bounds__(256) void gemm_bn_mfma_kernel(
    const unsigned short* __restrict__ a_bf,
    const float* __restrict__ stat_in, const float* __restrict__ gamma,
    const float* __restrict__ beta, float invN,
    const unsigned short* __restrict__ Wf, const float* __restrict__ bias,
    unsigned short* __restrict__ zout,
    float* __restrict__ stat_sum, float* __restrict__ stat_sq,
    int N, int mode)
{
    __shared__ unsigned short Wl[16384];   // 32 KB, fragment-ordered
    __shared__ float part[1024];
    __shared__ float scf[128], shf[128];

    int tid = threadIdx.x;
    {
        float4* dst = (float4*)Wl;
        const float4* srcp = (const float4*)Wf;
        #pragma unroll
        for (int i = 0; i < 8; ++i) dst[tid + i * 256] = srcp[tid + i * 256];
    }
    if (mode == 1 && tid < 128) {          // fused BN finalize (sum replicas)
        float ssum = 0.f, sqs = 0.f;
        #pragma unroll
        for (int r = 0; r < NREP; ++r) {
            ssum += stat_in[r * 512 + tid];
            sqs  += stat_in[r * 512 + 128 + tid];
        }
        float mean = ssum * invN;
        float var  = sqs * invN - mean * mean;
        float sv = gamma[tid] * rsqrtf(var + 1e-5f);
        scf[tid] = sv;
        shf[tid] = fmaf(-mean, sv, beta[tid]);
    }
    __syncthreads();

    int w = tid >> 6, lane = tid & 63, q = lane >> 4, n16 = lane & 15;
    int rowb = blockIdx.x * 128 + w * 16;
    int m0 = rowb + n16;
    int m1 = rowb + 64 + n16;
    int mc0 = (m0 < N) ? m0 : (N - 1);
    int mc1 = (m1 < N) ? m1 : (N - 1);
    const unsigned short* arow0 = a_bf + (size_t)mc0 * D;
    const unsigned short* arow1 = a_bf + (size_t)mc1 * D;

    f32x4 acc0[8], acc1[8];
    #pragma unroll
    for (int ct = 0; ct < 8; ++ct) {
        acc0[ct] = (f32x4){0.f, 0.f, 0.f, 0.f};
        acc1[ct] = (f32x4){0.f, 0.f, 0.f, 0.f};
    }

    #pragma unroll
    for (int kk = 0; kk < 4; ++kk) {
        int c = kk * 32 + q * 8;
        short8 af0, af1;
        if (mode == 0) {
            af0 = *(const short8*)(arow0 + c);
            af1 = *(const short8*)(arow1 + c);
        } else {
            af0 = bn_relu_pack(arow0, c, scf, shf);
            af1 = bn_relu_pack(arow1, c, scf, shf);
        }
        #pragma unroll
        for (int ct = 0; ct < 8; ++ct) {
            short8 bf = *(const short8*)&Wl[(((kk * 8 + ct) * 64) + lane) * 8];
            acc0[ct] = __builtin_amdgcn_mfma_f32_16x16x32_bf16(af0, bf, acc0[ct], 0, 0, 0);
            acc1[ct] = __builtin_amdgcn_mfma_f32_16x16x32_bf16(af1, bf, acc1[ct], 0, 0, 0);
        }
    }

    // epilogue: bias add, bf16 store, per-column stats (from fp32 values)
    #pragma unroll
    for (int ct = 0; ct < 8; ++ct) {
        int col = ct * 16 + n16;
        float bv = __ldg(bias + col);
        float s = 0.f, qs = 0.f;
        #pragma unroll
        for (int reg = 0; reg < 4; ++reg) {
            int row = rowb + q * 4 + reg;
            float v = acc0[ct][reg] + bv;
            if (row < N) {
                zout[(size_t)row * D + col] = f2bf(v);
                s += v;
                qs = fmaf(v, v, qs);
            }
        }
        #pragma unroll
        for (int reg = 0; reg < 4; ++reg) {
            int row = rowb + 64 + q * 4 + reg;
            float v = acc1[ct][reg] + bv;
            if (row < N) {
                zout[(size_t)row * D + col] = f2bf(v);
                s += v;
                qs = fmaf(v, v, qs);
            }
        }
        s  += __shfl_xor(s, 16, 64);
        s  += __shfl_xor(s, 32, 64);
        qs += __shfl_xor(qs, 16, 64);
        qs += __shfl_xor(qs, 32, 64);
        if (lane < 16) {
            part[w * 128 + col] = s;
            part[512 + w * 128 + col] = qs;
        }
    }
    __syncthreads();

    if (tid < 128) {
        int rep = ((int)blockIdx.x & (NREP - 1)) * 512;
        float s  = part[tid] + part[128 + tid] + part[256 + tid] + part[384 + tid];
        float qq = part[512 + tid] + part[640 + tid] + part[768 + tid] + part[896 + tid];
        atomicAdd(&stat_sum[rep + tid], s);
        atomicAdd(&stat_sq[rep + tid], qq);
    }
}

// ------- final BN + ReLU (fused BN2 finalize, sums NREP replicas) -------
__global__ __launch_bounds__(256) void bn_relu_kernel(
    const uint2* __restrict__ z2, float4* __restrict__ out,
    const float* __restrict__ stat2, const float* __restrict__ gamma,
    const float* __restrict__ beta, float invN, int total4)
{
    __shared__ float sf[128], tf[128];
    int tid = threadIdx.x;
    if (tid < 128) {
        float ssum = 0.f, sqs = 0.f;
        #pragma unroll
        for (int r = 0; r < NREP; ++r) {
            ssum += stat2[r * 512 + tid];
            sqs  += stat2[r * 512 + 128 + tid];
        }
        float mean = ssum * invN;
        float var  = sqs * invN - mean * mean;
        float sv = gamma[tid] * rsqrtf(var + 1e-5f);
        sf[tid] = sv;
        tf[tid] = fmaf(-mean, sv, beta[tid]);
    }
    __syncthreads();

    int i = blockIdx.x * 256 + tid;
    if (i >= total4) return;
    uint2 zp = z2[i];
    float2 v01 = bfpair2f(zp.x);
    float2 v23 = bfpair2f(zp.y);
    int c = (i & 31) * 4;
    float4 o;
    o.x = fmaxf(fmaf(v01.x, sf[c + 0], tf[c + 0]), 0.f);
    o.y = fmaxf(fmaf(v01.y, sf[c + 1], tf[c + 1]), 0.f);
    o.z = fmaxf(fmaf(v23.x, sf[c + 2], tf[c + 2]), 0.f);
    o.w = fmaxf(fmaf(v23.y, sf[c + 3], tf[c + 3]), 0.f);
    out[i] = o;
}

extern "C" void kernel_launch(void* const* d_in, const int* in_sizes, int n_in,
                              void* d_out, int out_size, void* d_ws, size_t ws_size,
                              hipStream_t stream)
{
    const float* x   = (const float*)d_in[0];
    const int*   ei  = (const int*)d_in[1];
    const float* eps = (const float*)d_in[2];
    const float* W1  = (const float*)d_in[3];
    const float* b1  = (const float*)d_in[4];
    const float* g1  = (const float*)d_in[5];
    const float* be1 = (const float*)d_in[6];
    const float* W2  = (const float*)d_in[7];
    const float* b2  = (const float*)d_in[8];
    const float* g2  = (const float*)d_in[9];
    const float* be2 = (const float*)d_in[10];

    int N = in_sizes[0] / D;       // 50000
    int E = in_sizes[1] / 2;       // 800000
    size_t ND = (size_t)N * D;
    int NB  = (N + 127) >> 7;      // 391 128-dst buckets

    // workspace layout (~25.8 MB):
    //   xh: ND+128 ushorts (row N = zeros); live through fused kernel
    //   region2 (ND ushorts): rec = NB*CAPB ints (4.4 MB) @ +0;
    //                         cursor (NB*CSTR ints, line-padded) @ +8 MB
    //                         -> z2 reuses region2 (gemm2+; rec/cursor dead)
    //   stats: NREP*512 floats, then Wf1/Wf2
    //   z1 lives in d_out (bf16, dead once bn_relu writes final fp32)
    unsigned short* xh  = (unsigned short*)d_ws;
    unsigned short* region2 = xh + ND + 128;
    unsigned* rec       = (unsigned*)region2;
    unsigned short* z2  = region2;
    int* cursor         = (int*)((char*)region2 + (8 << 20));
    float* stats        = (float*)(region2 + ND);
    unsigned short* Wf1 = (unsigned short*)(stats + 2 * NREP * 256);
    unsigned short* Wf2 = Wf1 + 16384;

    float* sum1 = stats + 0,   *sq1 = stats + 128;     // replica 0 bases
    float* sum2 = stats + 256, *sq2 = stats + 384;
    unsigned short* z1 = (unsigned short*)d_out;

    hipMemsetAsync(cursor, 0, NB * CSTR * sizeof(int), stream);

    int xtotal = N * 32;                      // float4 groups in x
    int xblocks = (xtotal + 255) / 256;
    int fblocks = (E + FB2 - 1) / FB2;        // 782 fill blocks
    prep_fill_kernel<<<fblocks + xblocks + 129, 256, 0, stream>>>(
        (const float4*)x, (uint2*)xh, xtotal, W1, W2, Wf1, Wf2,
        stats, xh + ND, xblocks, fblocks, ei, E, NB, cursor, rec);

    fused_gather_gemm1_kernel<<<NB, 512, 0, stream>>>(
        (const unsigned*)xh, rec, cursor, eps, Wf1, b1,
        z1, sum1, sq1, N, N * 256);

    int gblocks = (N + 127) / 128;
    gemm_bn_mfma_kernel<<<gblocks, 256, 0, stream>>>(
        z1, sum1, g1, be1, 1.0f / N,
        Wf2, b2, z2, sum2, sq2, N, 1);
    bn_relu_kernel<<<(N * 32 + 255) / 256, 256, 0, stream>>>(
        (const uint2*)z2, (float4*)d_out, sum2, g2, be2, 1.0f / N, N * 32);
}

// Round 17
// 196.164 us; speedup vs baseline: 1.0462x; 1.0095x over previous
//
#include <hip/hip_runtime.h>

#define D 128
#define FB2 1024      // edges per fill block (782 blocks: TLP for scatter phase)
#define CSTR 16       // cursor stride (ints) = one 64B line per bucket
#define CAPB 2816     // rec capacity per 128-dst bucket (mean 2048, +16 sigma)
#define SCAP 3456     // padded src-list capacity per 128-dst bucket
#define STAIL 3448    // run cap; slots 3448..3455 stay zoff pads
#define NREP 4        // stat-buffer replicas

typedef __attribute__((ext_vector_type(8))) short short8;
typedef __attribute__((ext_vector_type(4))) float f32x4;

union SP { int slist[SCAP]; float part[2048]; };

static __device__ __forceinline__ unsigned short f2bf(float f) {
    union { float f; unsigned u; } v; v.f = f;
    unsigned r = v.u + 0x7FFF + ((v.u >> 16) & 1);   // RNE
    return (unsigned short)(r >> 16);
}

static __device__ __forceinline__ float2 bfpair2f(unsigned p) {
    union { unsigned u; float f; } a, b;
    a.u = (p & 0xFFFFu) << 16;
    b.u = p & 0xFFFF0000u;
    return make_float2(a.f, b.f);
}

static __device__ __forceinline__ void acc2(f32x4& A, uint2 p) {
    union { unsigned u; float f; } t;
    float f0, f1, f2, f3;
    t.u = p.x << 16;          f0 = t.f;
    t.u = p.x & 0xFFFF0000u;  f1 = t.f;
    t.u = p.y << 16;          f2 = t.f;
    t.u = p.y & 0xFFFF0000u;  f3 = t.f;
    A[0] += f0; A[1] += f1; A[2] += f2; A[3] += f3;
}

// emit one gathered row into the fragment-ordered LDS A tile (XOR-swizzled).
static __device__ __forceinline__ void emitA(
    unsigned short* Al, int rloc, int valid,
    int e_kk, int e_q, int e_j0, float epsv, uint2 xv, f32x4 A)
{
    float r0 = 0.f, r1 = 0.f, r2 = 0.f, r3 = 0.f;
    if (valid) {
        union { unsigned u; float f; } t;
        float x0, x1, x2, x3;
        t.u = xv.x << 16;          x0 = t.f;
        t.u = xv.x & 0xFFFF0000u;  x1 = t.f;
        t.u = xv.y << 16;          x2 = t.f;
        t.u = xv.y & 0xFFFF0000u;  x3 = t.f;
        r0 = fmaf(epsv, x0, A[0]);
        r1 = fmaf(epsv, x1, A[1]);
        r2 = fmaf(epsv, x2, A[2]);
        r3 = fmaf(epsv, x3, A[3]);
    }
    uint2 o;
    o.x = (unsigned)f2bf(r0) | ((unsigned)f2bf(r1) << 16);
    o.y = (unsigned)f2bf(r2) | ((unsigned)f2bf(r3) << 16);
    int w = rloc >> 4, rl = rloc & 15;
    int k5 = (e_kk << 2) | e_q;
    unsigned addr = (unsigned)(w * 2048 + e_kk * 512 + e_q * 128
                               + ((rl ^ k5) << 3) + e_j0);
    *(uint2*)(Al + addr) = o;
}

// ------- fused prep + fill (fill blocks FIRST): edges register-staged (single
//         global read of ei), fill into fixed-capacity 128-dst rec segments;
//         then x->bf16, W->fragments, stats/zrow zero. cursor line-padded. -------
__global__ __launch_bounds__(256) void prep_fill_kernel(
    const float4* __restrict__ x4, uint2* __restrict__ xh, int xtotal,
    const float* __restrict__ W1, const float* __restrict__ W2,
    unsigned short* __restrict__ Wf1, unsigned short* __restrict__ Wf2,
    float* __restrict__ stats, unsigned short* __restrict__ zrow,
    int xblocks, int fblocks,
    const int* __restrict__ ei, int E, int NB,
    int* __restrict__ cursor, unsigned* __restrict__ rec)
{
    __shared__ int hist[512], base[512];
    int tid = threadIdx.x;

    if (blockIdx.x < (unsigned)fblocks) {
        // ---- fill range (scheduled first: the long pole) ----
        int b0 = (int)blockIdx.x * FB2;
        int lim = min(FB2, E - b0);
        int dreg[4], sreg[4];
        #pragma unroll
        for (int k = 0; k < 4; ++k) {
            int i = k * 256 + tid;
            if (i < lim) {
                dreg[k] = ei[E + b0 + i];
                sreg[k] = ei[b0 + i];
            } else { dreg[k] = -1; sreg[k] = 0; }
        }
        for (int i = tid; i < NB; i += 256) hist[i] = 0;
        __syncthreads();
        #pragma unroll
        for (int k = 0; k < 4; ++k)
            if (dreg[k] >= 0) atomicAdd(&hist[dreg[k] >> 7], 1);
        __syncthreads();
        for (int i = tid; i < NB; i += 256) {
            int c = hist[i];
            base[i] = c ? atomicAdd(&cursor[i * CSTR], c) : 0;
            hist[i] = 0;   // reuse as rank counter
        }
        __syncthreads();
        #pragma unroll
        for (int k = 0; k < 4; ++k) {
            if (dreg[k] >= 0) {
                int bk = dreg[k] >> 7;
                int r = atomicAdd(&hist[bk], 1);
                int slot = base[bk] + r;
                if (slot < CAPB)
                    rec[(unsigned)bk * CAPB + slot] =
                        ((unsigned)sreg[k] << 7) | (unsigned)(dreg[k] & 127);
            }
        }
        return;
    }
    int bx = (int)blockIdx.x - fblocks;
    if (bx < xblocks) {
        int i = bx * 256 + tid;
        if (i >= xtotal) return;
        float4 v = x4[i];
        uint2 o;
        o.x = (unsigned)f2bf(v.x) | ((unsigned)f2bf(v.y) << 16);
        o.y = (unsigned)f2bf(v.z) | ((unsigned)f2bf(v.w) << 16);
        xh[i] = o;
        return;
    }
    if (bx < xblocks + 128) {
        int idx = (bx - xblocks) * 256 + tid;   // 0..32767
        const float* W = (idx < 16384) ? W1 : W2;
        unsigned short* Wf = (idx < 16384) ? Wf1 : Wf2;
        int e = idx & 16383;
        int j = e & 7, lane = (e >> 3) & 63, ckk = e >> 9;
        int ct = ckk & 7, kk = ckk >> 3;
        int k = kk * 32 + (lane >> 4) * 8 + j;
        int n = ct * 16 + (lane & 15);
        Wf[e] = f2bf(W[k * 128 + n]);
        return;
    }
    // stats + zrow zero
    #pragma unroll
    for (int i = 0; i < 2 * NREP; ++i) stats[tid + i * 256] = 0.f;
    if (tid < 128) zrow[tid] = 0;
}

// ------- fused subsort + gather + GEMM1 + BN1-stat: one block per 128-dst bucket.
//         r16 structure; tid0 serial offs-scan replaced by wave-0 shfl prefix
//         (clamp composes: run = min(sum, STAIL), exact equivalence). -------
__global__ __launch_bounds__(512) void fused_gather_gemm1_kernel(
    const unsigned* __restrict__ xh, const unsigned* __restrict__ rec,
    const int* __restrict__ cnt_g, const float* __restrict__ epsp,
    const unsigned short* __restrict__ Wf, const float* __restrict__ bias,
    unsigned short* __restrict__ z1out,
    float* __restrict__ stat_sum, float* __restrict__ stat_sq,
    int N, int zoff)
{
    __shared__ unsigned short Wl[16384];   // 32 KB W fragments
    __shared__ unsigned short Al[16384];   // 32 KB A fragments (8 tiles x 16 rows)
    __shared__ SP u;                       // slist (phase 1/2) | part (phase 3)
    __shared__ int cnt[128], rnk[128], offs[129];

    int tid = threadIdx.x;
    int g = blockIdx.x;
    int d0 = g << 7;

    {   // stage W: 2048 float4 over 512 threads
        float4* dst = (float4*)Wl;
        const float4* srcp = (const float4*)Wf;
        #pragma unroll
        for (int i = 0; i < 4; ++i) dst[tid + i * 512] = srcp[tid + i * 512];
    }
    if (tid < 128) { cnt[tid] = 0; rnk[tid] = 0; }
    for (int i = tid; i < SCAP; i += 512) u.slist[i] = zoff;
    __syncthreads();

    int cv = cnt_g[g * CSTR];
    if (cv > CAPB) cv = CAPB;
    int lo = g * CAPB, hi = lo + cv;

    for (int i = lo + tid; i < hi; i += 512)
        atomicAdd(&cnt[rec[i] & 127], 1);
    __syncthreads();
    if (tid < 64) {      // wave-0 parallel exclusive prefix of padded counts
        int p0 = (cnt[2 * tid] + 7) & ~7;
        int p1 = (cnt[2 * tid + 1] + 7) & ~7;
        int s = p0 + p1;
        #pragma unroll
        for (int off = 1; off < 64; off <<= 1) {
            int t = __shfl_up(s, off, 64);
            if (tid >= off) s += t;
        }
        int excl = s - p0 - p1;
        offs[2 * tid]     = (excl < STAIL) ? excl : STAIL;
        int e1 = excl + p0;
        offs[2 * tid + 1] = (e1 < STAIL) ? e1 : STAIL;
        if (tid == 63) offs[128] = (s < STAIL) ? s : STAIL;
    }
    __syncthreads();
    for (int i = lo + tid; i < hi; i += 512) {
        unsigned r = rec[i];
        int d = r & 127;
        int rk = atomicAdd(&rnk[d], 1);
        int slot = offs[d] + rk;
        if (slot < offs[d + 1]) u.slist[slot] = (int)((r >> 7) << 8);  // src*256
    }
    __syncthreads();

    int wv = tid >> 6, lane = tid & 63;
    int half = lane >> 5, l5 = lane & 31;
    unsigned lane8 = (unsigned)(l5 << 3);
    float epsv = 1.0f + __ldg(epsp);
    const char* xc = (const char*)xh;

    // emit-address components for lane l5 (owns cols c0 = l5*4 .. c0+3)
    int e_kk = l5 >> 3;
    int e_q  = (l5 >> 1) & 3;
    int e_j0 = (l5 & 1) * 4;

    #pragma unroll 1
    for (int p = 0; p < 4; ++p) {
        int dloc = p * 32 + wv * 4;
        int dA = d0 + dloc, dB = dA + 1, dC = dA + 2, dD = dA + 3;
        int vA = (dA < N), vB = (dB < N), vC = (dC < N), vD = (dD < N);

        int s0 = offs[dloc + 0], s1 = offs[dloc + 1];
        int s2 = offs[dloc + 2], s3 = offs[dloc + 3], s4 = offs[dloc + 4];
        int nch0 = (s1 - s0) >> 3, nch1 = (s2 - s1) >> 3;
        int nch2 = (s3 - s2) >> 3, nch3 = (s4 - s3) >> 3;
        int iters = max(max(nch0, nch1), max(nch2, nch3));

        uint2 xv0 = *(const uint2*)(xc + (unsigned)((vA ? dA : 0) * 256) + lane8);
        uint2 xv1 = *(const uint2*)(xc + (unsigned)((vB ? dB : 0) * 256) + lane8);
        uint2 xv2 = *(const uint2*)(xc + (unsigned)((vC ? dC : 0) * 256) + lane8);
        uint2 xv3 = *(const uint2*)(xc + (unsigned)((vD ? dD : 0) * 256) + lane8);

        f32x4 A0 = (f32x4){0.f, 0.f, 0.f, 0.f};
        f32x4 A1 = (f32x4){0.f, 0.f, 0.f, 0.f};
        f32x4 A2 = (f32x4){0.f, 0.f, 0.f, 0.f};
        f32x4 A3 = (f32x4){0.f, 0.f, 0.f, 0.f};

        for (int c = 0; c < iters; ++c) {
            int b0 = (c < nch0) ? (s0 + (c << 3)) : STAIL;   // STAIL.. = zoff pads
            int b1 = (c < nch1) ? (s1 + (c << 3)) : STAIL;
            int b2 = (c < nch2) ? (s2 + (c << 3)) : STAIL;
            int b3 = (c < nch3) ? (s3 + (c << 3)) : STAIL;
            uint2 p0[4], p1[4], p2[4], p3[4];
            #pragma unroll
            for (int k = 0; k < 4; ++k) {
                unsigned o0 = (unsigned)u.slist[b0 + 2 * k + half];
                unsigned o1 = (unsigned)u.slist[b1 + 2 * k + half];
                unsigned o2 = (unsigned)u.slist[b2 + 2 * k + half];
                unsigned o3 = (unsigned)u.slist[b3 + 2 * k + half];
                p0[k] = *(const uint2*)(xc + (o0 + lane8));
                p1[k] = *(const uint2*)(xc + (o1 + lane8));
                p2[k] = *(const uint2*)(xc + (o2 + lane8));
                p3[k] = *(const uint2*)(xc + (o3 + lane8));
            }
            #pragma unroll
            for (int k = 0; k < 4; ++k) {
                acc2(A0, p0[k]); acc2(A1, p1[k]);
                acc2(A2, p2[k]); acc2(A3, p3[k]);
            }
        }

        #pragma unroll
        for (int r = 0; r < 4; ++r) {
            A0[r] += __shfl_xor(A0[r], 32, 64);
            A1[r] += __shfl_xor(A1[r], 32, 64);
            A2[r] += __shfl_xor(A2[r], 32, 64);
            A3[r] += __shfl_xor(A3[r], 32, 64);
        }

        if (half == 0) {
            emitA(Al, dloc + 0, vA, e_kk, e_q, e_j0, epsv, xv0, A0);
            emitA(Al, dloc + 1, vB, e_kk, e_q, e_j0, epsv, xv1, A1);
            emitA(Al, dloc + 2, vC, e_kk, e_q, e_j0, epsv, xv2, A2);
            emitA(Al, dloc + 3, vD, e_kk, e_q, e_j0, epsv, xv3, A3);
        }
    }
    __syncthreads();   // A tile complete; slist dead (part may alias now)

    // ---- MFMA phase: wave wv owns rows d0+wv*16..+15; swizzled A read ----
    int q = lane >> 4, n16 = lane & 15;
    f32x4 acc[8];
    #pragma unroll
    for (int ct = 0; ct < 8; ++ct) acc[ct] = (f32x4){0.f, 0.f, 0.f, 0.f};

    #pragma unroll
    for (int kk = 0; kk < 4; ++kk) {
        int k5 = (kk << 2) | q;
        short8 af = *(const short8*)&Al[wv * 2048 + kk * 512 + q * 128
                                        + ((n16 ^ k5) << 3)];
        #pragma unroll
        for (int ct = 0; ct < 8; ++ct) {
            short8 bf = *(const short8*)&Wl[(((kk * 8 + ct) * 64) + lane) * 8];
            acc[ct] = __builtin_amdgcn_mfma_f32_16x16x32_bf16(af, bf, acc[ct], 0, 0, 0);
        }
    }

    int rowb = d0 + wv * 16;
    #pragma unroll
    for (int ct = 0; ct < 8; ++ct) {
        int col = ct * 16 + n16;
        float bv = __ldg(bias + col);
        float s = 0.f, qs = 0.f;
        #pragma unroll
        for (int reg = 0; reg < 4; ++reg) {
            int row = rowb + q * 4 + reg;
            float v = acc[ct][reg] + bv;
            if (row < N) {
                z1out[(size_t)row * D + col] = f2bf(v);
                s += v;
                qs = fmaf(v, v, qs);
            }
        }
        s  += __shfl_xor(s, 16, 64);
        s  += __shfl_xor(s, 32, 64);
        qs += __shfl_xor(qs, 16, 64);
        qs += __shfl_xor(qs, 32, 64);
        if (lane < 16) {
            u.part[wv * 128 + col] = s;
            u.part[1024 + wv * 128 + col] = qs;
        }
    }
    __syncthreads();

    if (tid < 128) {
        float s = 0.f, qq = 0.f;
        #pragma unroll
        for (int w = 0; w < 8; ++w) {
            s  += u.part[w * 128 + tid];
            qq += u.part[1024 + w * 128 + tid];
        }
        int rep = ((int)blockIdx.x & (NREP - 1)) * 512;
        atomicAdd(&stat_sum[rep + tid], s);
        atomicAdd(&stat_sq[rep + tid], qq);
    }
}

static __device__ __forceinline__ short8 bn_relu_pack(
    const unsigned short* arow, int c, const float* scf, const float* shf)
{
    uint4 rw = *(const uint4*)(arow + c);
    float2 p0 = bfpair2f(rw.x), p1 = bfpair2f(rw.y);
    float2 p2 = bfpair2f(rw.z), p3 = bfpair2f(rw.w);
    p0.x = fmaxf(fmaf(p0.x, scf[c + 0], shf[c + 0]), 0.f);
    p0.y = fmaxf(fmaf(p0.y, scf[c + 1], shf[c + 1]), 0.f);
    p1.x = fmaxf(fmaf(p1.x, scf[c + 2], shf[c + 2]), 0.f);
    p1.y = fmaxf(fmaf(p1.y, scf[c + 3], shf[c + 3]), 0.f);
    p2.x = fmaxf(fmaf(p2.x, scf[c + 4], shf[c + 4]), 0.f);
    p2.y = fmaxf(fmaf(p2.y, scf[c + 5], shf[c + 5]), 0.f);
    p3.x = fmaxf(fmaf(p3.x, scf[c + 6], shf[c + 6]), 0.f);
    p3.y = fmaxf(fmaf(p3.y, scf[c + 7], shf[c + 7]), 0.f);
    short8 af;
    af[0] = (short)f2bf(p0.x); af[1] = (short)f2bf(p0.y);
    af[2] = (short)f2bf(p1.x); af[3] = (short)f2bf(p1.y);
    af[4] = (short)f2bf(p2.x); af[5] = (short)f2bf(p2.y);
    af[6] = (short)f2bf(p3.x); af[7] = (short)f2bf(p3.y);
    return af;
}

// ---------------- MFMA GEMM2 + BN2-stat (bf16 in/out), fused BN1 finalize ----------------
__global__ __launch_bounds__(256) void gemm_bn_mfma_kernel(
    const unsigned short* __restrict__ a_bf,
    const float* __restrict__ stat_in, const float* __restrict__ gamma,
    const float* __restrict__ beta, float invN,
    const unsigned short* __restrict__ Wf, const float* __restrict__ bias,
    unsigned short* __restrict__ zout,
    float* __restrict__ stat_sum, float* __restrict__ stat_sq,
    int N, int mode)
{
    __shared__ unsigned short Wl[16384];   // 32 KB, fragment-ordered
    __shared__ float part[1024];
    __shared__ float scf[128], shf[128];

    int tid = threadIdx.x;
    {
        float4* dst = (float4*)Wl;
        const float4* srcp = (const float4*)Wf;
        #pragma unroll
        for (int i = 0; i < 8; ++i) dst[tid + i * 256] = srcp[tid + i * 256];
    }
    if (mode == 1 && tid < 128) {          // fused BN finalize (sum replicas)
        float ssum = 0.f, sqs = 0.f;
        #pragma unroll
        for (int r = 0; r < NREP; ++r) {
            ssum += stat_in[r * 512 + tid];
            sqs  += stat_in[r * 512 + 128 + tid];
        }
        float mean = ssum * invN;
        float var  = sqs * invN - mean * mean;
        float sv = gamma[tid] * rsqrtf(var + 1e-5f);
        scf[tid] = sv;
        shf[tid] = fmaf(-mean, sv, beta[tid]);
    }
    __syncthreads();

    int w = tid >> 6, lane = tid & 63, q = lane >> 4, n16 = lane & 15;
    int rowb = blockIdx.x * 128 + w * 16;
    int m0 = rowb + n16;
    int m1 = rowb + 64 + n16;
    int mc0 = (m0 < N) ? m0 : (N - 1);
    int mc1 = (m1 < N) ? m1 : (N - 1);
    const unsigned short* arow0 = a_bf + (size_t)mc0 * D;
    const unsigned short* arow1 = a_bf + (size_t)mc1 * D;

    f32x4 acc0[8], acc1[8];
    #pragma unroll
    for (int ct = 0; ct < 8; ++ct) {
        acc0[ct] = (f32x4){0.f, 0.f, 0.f, 0.f};
        acc1[ct] = (f32x4){0.f, 0.f, 0.f, 0.f};
    }

    #pragma unroll
    for (int kk = 0; kk < 4; ++kk) {
        int c = kk * 32 + q * 8;
        short8 af0, af1;
        if (mode == 0) {
            af0 = *(const short8*)(arow0 + c);
            af1 = *(const short8*)(arow1 + c);
        } else {
            af0 = bn_relu_pack(arow0, c, scf, shf);
            af1 = bn_relu_pack(arow1, c, scf, shf);
        }
        #pragma unroll
        for (int ct = 0; ct < 8; ++ct) {
            short8 bf = *(const short8*)&Wl[(((kk * 8 + ct) * 64) + lane) * 8];
            acc0[ct] = __builtin_amdgcn_mfma_f32_16x16x32_bf16(af0, bf, acc0[ct], 0, 0, 0);
            acc1[ct] = __builtin_amdgcn_mfma_f32_16x16x32_bf16(af1, bf, acc1[ct], 0, 0, 0);
        }
    }

    // epilogue: bias add, bf16 store, per-column stats (from fp32 values)
    #pragma unroll
    for (int ct = 0; ct < 8; ++ct) {
        int col = ct * 16 + n16;
        float bv = __ldg(bias + col);
        float s = 0.f, qs = 0.f;
        #pragma unroll
        for (int reg = 0; reg < 4; ++reg) {
            int row = rowb + q * 4 + reg;
            float v = acc0[ct][reg] + bv;
            if (row < N) {
                zout[(size_t)row * D + col] = f2bf(v);
                s += v;
                qs = fmaf(v, v, qs);
            }
        }
        #pragma unroll
        for (int reg = 0; reg < 4; ++reg) {
            int row = rowb + 64 + q * 4 + reg;
            float v = acc1[ct][reg] + bv;
            if (row < N) {
                zout[(size_t)row * D + col] = f2bf(v);
                s += v;
                qs = fmaf(v, v, qs);
            }
        }
        s  += __shfl_xor(s, 16, 64);
        s  += __shfl_xor(s, 32, 64);
        qs += __shfl_xor(qs, 16, 64);
        qs += __shfl_xor(qs, 32, 64);
        if (lane < 16) {
            part[w * 128 + col] = s;
            part[512 + w * 128 + col] = qs;
        }
    }
    __syncthreads();

    if (tid < 128) {
        int rep = ((int)blockIdx.x & (NREP - 1)) * 512;
        float s  = part[tid] + part[128 + tid] + part[256 + tid] + part[384 + tid];
        float qq = part[512 + tid] + part[640 + tid] + part[768 + tid] + part[896 + tid];
        atomicAdd(&stat_sum[rep + tid], s);
        atomicAdd(&stat_sq[rep + tid], qq);
    }
}

// ------- final BN + ReLU (fused BN2 finalize, sums NREP replicas) -------
__global__ __launch_bounds__(256) void bn_relu_kernel(
    const uint2* __restrict__ z2, float4* __restrict__ out,
    const float* __restrict__ stat2, const float* __restrict__ gamma,
    const float* __restrict__ beta, float invN, int total4)
{
    __shared__ float sf[128], tf[128];
    int tid = threadIdx.x;
    if (tid < 128) {
        float ssum = 0.f, sqs = 0.f;
        #pragma unroll
        for (int r = 0; r < NREP; ++r) {
            ssum += stat2[r * 512 + tid];
            sqs  += stat2[r * 512 + 128 + tid];
        }
        float mean = ssum * invN;
        float var  = sqs * invN - mean * mean;
        float sv = gamma[tid] * rsqrtf(var + 1e-5f);
        sf[tid] = sv;
        tf[tid] = fmaf(-mean, sv, beta[tid]);
    }
    __syncthreads();

    int i = blockIdx.x * 256 + tid;
    if (i >= total4) return;
    uint2 zp = z2[i];
    float2 v01 = bfpair2f(zp.x);
    float2 v23 = bfpair2f(zp.y);
    int c = (i & 31) * 4;
    float4 o;
    o.x = fmaxf(fmaf(v01.x, sf[c + 0], tf[c + 0]), 0.f);
    o.y = fmaxf(fmaf(v01.y, sf[c + 1], tf[c + 1]), 0.f);
    o.z = fmaxf(fmaf(v23.x, sf[c + 2], tf[c + 2]), 0.f);
    o.w = fmaxf(fmaf(v23.y, sf[c + 3], tf[c + 3]), 0.f);
    out[i] = o;
}

extern "C" void kernel_launch(void* const* d_in, const int* in_sizes, int n_in,
                              void* d_out, int out_size, void* d_ws, size_t ws_size,
                              hipStream_t stream)
{
    const float* x   = (const float*)d_in[0];
    const int*   ei  = (const int*)d_in[1];
    const float* eps = (const float*)d_in[2];
    const float* W1  = (const float*)d_in[3];
    const float* b1  = (const float*)d_in[4];
    const float* g1  = (const float*)d_in[5];
    const float* be1 = (const float*)d_in[6];
    const float* W2  = (const float*)d_in[7];
    const float* b2  = (const float*)d_in[8];
    const float* g2  = (const float*)d_in[9];
    const float* be2 = (const float*)d_in[10];

    int N = in_sizes[0] / D;       // 50000
    int E = in_sizes[1] / 2;       // 800000
    size_t ND = (size_t)N * D;
    int NB  = (N + 127) >> 7;      // 391 128-dst buckets

    // workspace layout (~25.8 MB):
    //   xh: ND+128 ushorts (row N = zeros); live through fused kernel
    //   region2 (ND ushorts): rec = NB*CAPB ints (4.4 MB) @ +0;
    //                         cursor (NB*CSTR ints, line-padded) @ +8 MB
    //                         -> z2 reuses region2 (gemm2+; rec/cursor dead)
    //   stats: NREP*512 floats, then Wf1/Wf2
    //   z1 lives in d_out (bf16, dead once bn_relu writes final fp32)
    unsigned short* xh  = (unsigned short*)d_ws;
    unsigned short* region2 = xh + ND + 128;
    unsigned* rec       = (unsigned*)region2;
    unsigned short* z2  = region2;
    int* cursor         = (int*)((char*)region2 + (8 << 20));
    float* stats        = (float*)(region2 + ND);
    unsigned short* Wf1 = (unsigned short*)(stats + 2 * NREP * 256);
    unsigned short* Wf2 = Wf1 + 16384;

    float* sum1 = stats + 0,   *sq1 = stats + 128;     // replica 0 bases
    float* sum2 = stats + 256, *sq2 = stats + 384;
    unsigned short* z1 = (unsigned short*)d_out;

    hipMemsetAsync(cursor, 0, NB * CSTR * sizeof(int), stream);

    int xtotal = N * 32;                      // float4 groups in x
    int xblocks = (xtotal + 255) / 256;
    int fblocks = (E + FB2 - 1) / FB2;        // 782 fill blocks
    prep_fill_kernel<<<fblocks + xblocks + 129, 256, 0, stream>>>(
        (const float4*)x, (uint2*)xh, xtotal, W1, W2, Wf1, Wf2,
        stats, xh + ND, xblocks, fblocks, ei, E, NB, cursor, rec);

    fused_gather_gemm1_kernel<<<NB, 512, 0, stream>>>(
        (const unsigned*)xh, rec, cursor, eps, Wf1, b1,
        z1, sum1, sq1, N, N * 256);

    int gblocks = (N + 127) / 128;
    gemm_bn_mfma_kernel<<<gblocks, 256, 0, stream>>>(
        z1, sum1, g1, be1, 1.0f / N,
        Wf2, b2, z2, sum2, sq2, N, 1);
    bn_relu_kernel<<<(N * 32 + 255) / 256, 256, 0, stream>>>(
        (const uint2*)z2, (float4*)d_out, sum2, g2, be2, 1.0f / N, N * 32);
}